// Round 2
// 405.271 us; speedup vs baseline: 1.0591x; 1.0591x over previous
//
#include <hip/hip_runtime.h>

#define BN 8192

typedef __attribute__((ext_vector_type(8))) __bf16 bf16x8;
typedef __attribute__((ext_vector_type(4))) float float4v;

__device__ inline unsigned short f2bf(float f) {
  union { float f; unsigned u; } v;
  v.f = f;
  unsigned r = v.u + 0x7FFFu + ((v.u >> 16) & 1u);
  return (unsigned short)(r >> 16);
}

// Kernel 1: per-row reciprocal L2 norms (fp32) + fp32->bf16 pack of A and B.
__global__ __launch_bounds__(256) void prep_kernel(
    const float* __restrict__ fa, const float* __restrict__ fb,
    unsigned short* __restrict__ abf, unsigned short* __restrict__ bbf,
    float* __restrict__ rna, float* __restrict__ rnb) {
  const int wave = threadIdx.x >> 6, lane = threadIdx.x & 63;
  const int w = blockIdx.x * 4 + wave;
  const int mat = w >> 13;            // 0 = A, 1 = B
  const int row = w & (BN - 1);
  const float* src = mat ? fb : fa;
  unsigned short* dst = mat ? bbf : abf;
  float* nrm = mat ? rnb : rna;
  const float2 v = ((const float2*)src)[row * 64 + lane];
  float s = v.x * v.x + v.y * v.y;
#pragma unroll
  for (int m = 32; m >= 1; m >>= 1) s += __shfl_xor(s, m, 64);
  ushort2 h;
  h.x = f2bf(v.x);
  h.y = f2bf(v.y);
  ((ushort2*)dst)[row * 64 + lane] = h;
  if (lane == 0) nrm[row] = 1.0f / sqrtf(s);  // norms ~sqrt(128); eps clamp vacuous
}

// Kernel 2: 128x128 tile of cos = (A @ B^T) * rna * rnb, bf16 MFMA.
// No A/B LDS staging: MFMA fragments (16 contiguous bytes per lane) are loaded
// straight from the L2-resident bf16 panels. LDS = 32KB half-tile Cs used in
// two epilogue passes -> 34KB/block -> 4 blocks/CU (vs 2 before).
// Writeback: +1-dword shifted Cs rows give ALIGNED dwordx4 global stores
// (cols 3..126 by 31 lanes/halfwave; lane 31 stores cols 0,1,2,127 scalar).
__global__ __launch_bounds__(256, 4) void gemm_kernel(
    const unsigned short* __restrict__ abf, const unsigned short* __restrict__ bbf,
    const float* __restrict__ rna, const float* __restrict__ rnb,
    const int* __restrict__ lab,
    float* __restrict__ out,            // out[0]=loss, out+1 = cos[8192][8192]
    float* __restrict__ lrow, float* __restrict__ srow) {
  __shared__ alignas(16) float Cs[64 * 128];   // 32 KB, rows shifted+rotated
  __shared__ int labr[128], labc[128];
  __shared__ float rnaS[128], rnbS[128];

  const int tid = threadIdx.x;
  const int wave = tid >> 6, lane = tid & 63;
  const int quad = lane >> 4, lcol = lane & 15;
  const int bx = blockIdx.x, by = blockIdx.y;

  if (tid < 128) {
    labr[tid] = lab[by * 128 + tid];
    rnaS[tid] = rna[by * 128 + tid];
  } else {
    labc[tid - 128] = lab[bx * 128 + (tid - 128)];
    rnbS[tid - 128] = rnb[bx * 128 + (tid - 128)];
  }

  const int m0 = (wave >> 1) * 64;   // wave's local row base
  const int n0 = (wave & 1) * 64;    // wave's local col base

  // Direct global fragment bases: lane (quad,lcol) holds row lcol(+i*16),
  // k = kb*32 + quad*8 .. +7  -> 16B contiguous, 16B aligned.
  const unsigned short* pa = abf + (size_t)(by * 128 + m0 + lcol) * 128 + quad * 8;
  const unsigned short* pb = bbf + (size_t)(bx * 128 + n0 + lcol) * 128 + quad * 8;

  float4v acc[4][4];
#pragma unroll
  for (int i = 0; i < 4; ++i)
#pragma unroll
    for (int j = 0; j < 4; ++j) acc[i][j] = float4v{0.f, 0.f, 0.f, 0.f};

#pragma unroll 1   // keep frag live-range = one kb step (reg budget for 4 blocks/CU)
  for (int kb = 0; kb < 4; ++kb) {
    bf16x8 af[4], bfr[4];
#pragma unroll
    for (int i = 0; i < 4; ++i) {
      af[i]  = *(const bf16x8*)(pa + (size_t)i * 2048 + kb * 32);
      bfr[i] = *(const bf16x8*)(pb + (size_t)i * 2048 + kb * 32);
    }
#pragma unroll
    for (int i = 0; i < 4; ++i)
#pragma unroll
      for (int j = 0; j < 4; ++j)
        acc[i][j] = __builtin_amdgcn_mfma_f32_16x16x32_bf16(af[i], bfr[j], acc[i][j], 0, 0, 0);
  }

  __syncthreads();   // labr/labc/rnaS/rnbS ready

  float rnbv[4];
  int labcv[4];
#pragma unroll
  for (int j = 0; j < 4; ++j) {
    const int cl = n0 + j * 16 + lcol;
    rnbv[j] = rnbS[cl];
    labcv[j] = labc[cl];
  }

#pragma unroll
  for (int p = 0; p < 2; ++p) {
    // --- Epilogue compute for i = 2p, 2p+1 into half-tile Cs.
    // C/D layout: col = lane&15 (+j*16), row = quad*4 + reg (+i*16).
#pragma unroll
    for (int ih = 0; ih < 2; ++ih) {
      const int i = 2 * p + ih;
      int rowt[4], labrv[4];
      float rnav[4], accE[4], accS[4];
#pragma unroll
      for (int r = 0; r < 4; ++r) {
        rowt[r] = m0 + i * 16 + quad * 4 + r;
        labrv[r] = labr[rowt[r]];
        rnav[r] = rnaS[rowt[r]];
        accE[r] = 0.f; accS[r] = 0.f;
      }
      const int lrb = (m0 ? 32 : 0) + ih * 16 + quad * 4;  // Cs local row base
#pragma unroll
      for (int j = 0; j < 4; ++j) {
        const int col = n0 + j * 16 + lcol;
        const int cd = (col + 1 + quad * 8) & 127;  // +1 align shift, quad*8 bank rot
#pragma unroll
        for (int r = 0; r < 4; ++r) {
          const float cv = acc[i][j][r] * rnav[r] * rnbv[j];
          Cs[(lrb + r) * 128 + cd] = cv;
          accE[r] += __expf(cv - 1.0f);
          if (labrv[r] == labcv[j]) accS[r] += cv;
        }
      }
#pragma unroll
      for (int r = 0; r < 4; ++r) {
#pragma unroll
        for (int m = 1; m <= 8; m <<= 1) {
          accE[r] += __shfl_xor(accE[r], m, 64);
          accS[r] += __shfl_xor(accS[r], m, 64);
        }
      }
      if (lcol == 0) {
#pragma unroll
        for (int r = 0; r < 4; ++r) {
          const int grow = by * 128 + rowt[r];
          atomicAdd(&lrow[grow], accE[r]);
          atomicAdd(&srow[grow], accS[r]);
        }
      }
    }
    __syncthreads();   // half-tile Cs complete

    // --- Aligned vectorized writeback: half-wave per row, 2 rows/iter.
    const int k = lane & 31, h = lane >> 5;
#pragma unroll
    for (int t = 0; t < 8; ++t) {
      const int lr = wave * 16 + 2 * t + h;              // Cs local row 0..63
      const int R = ((lr >> 2) & 3) * 8;                 // writer's quad*8 rotation
      const int d = (k == 31) ? R : ((4 * k + 4 + R) & 127);
      const float4v v = *(const float4v*)&Cs[lr * 128 + d];
      const int trow = (lr >> 5) * 64 + (2 * p + ((lr >> 4) & 1)) * 16 + (lr & 15);
      float* base = out + 1 + ((size_t)(by * 128 + trow) << 13) + bx * 128;
      if (k < 31) {
        __builtin_nontemporal_store(v, (float4v*)(base + 3 + 4 * k));  // cols 3+4k..6+4k
      } else {
        __builtin_nontemporal_store(v[1], base);          // col 0
        __builtin_nontemporal_store(v[2], base + 1);      // col 1
        __builtin_nontemporal_store(v[3], base + 2);      // col 2
        __builtin_nontemporal_store(v[0], base + 127);    // col 127
      }
    }
    if (p == 0) __syncthreads();   // Cs reads done before pass-1 overwrites
  }
}

// Kernel 3: loss = -sum_i [S_i - C_i*(1 + log l_i)] / B^2, single block.
// C_i = hist[label_i] (exact count, no need to accumulate in gemm).
__global__ __launch_bounds__(1024) void loss_kernel(
    const int* __restrict__ lab, const float* __restrict__ lrow,
    const float* __restrict__ srow, float* __restrict__ out) {
  __shared__ int hist[2048];
  __shared__ float red[1024];
  for (int i = threadIdx.x; i < 2048; i += 1024) hist[i] = 0;
  __syncthreads();
  for (int i = threadIdx.x; i < BN; i += 1024) atomicAdd(&hist[lab[i]], 1);
  __syncthreads();
  float p = 0.f;
  for (int i = threadIdx.x; i < BN; i += 1024)
    p += srow[i] - (float)hist[lab[i]] * (1.0f + __logf(lrow[i]));
  red[threadIdx.x] = p;
  __syncthreads();
  for (int s = 512; s >= 1; s >>= 1) {
    if (threadIdx.x < s) red[threadIdx.x] += red[threadIdx.x + s];
    __syncthreads();
  }
  if (threadIdx.x == 0) out[0] = -red[0] / 67108864.0f;  // B*B = 2^26 exact
}

extern "C" void kernel_launch(void* const* d_in, const int* in_sizes, int n_in,
                              void* d_out, int out_size, void* d_ws, size_t ws_size,
                              hipStream_t stream) {
  const int* lab = (const int*)d_in[0];
  const float* fa = (const float*)d_in[1];
  const float* fb = (const float*)d_in[2];
  float* out = (float*)d_out;

  char* ws = (char*)d_ws;
  unsigned short* abf = (unsigned short*)ws;                          // 2 MB
  unsigned short* bbf = (unsigned short*)(ws + (2u << 20));           // 2 MB
  float* rna  = (float*)(ws + (4u << 20));                            // 32 KB
  float* rnb  = (float*)(ws + (4u << 20) + 32768);                    // 32 KB
  float* lrow = (float*)(ws + (4u << 20) + 2 * 32768);                // 32 KB
  float* srow = (float*)(ws + (4u << 20) + 3 * 32768);                // 32 KB

  hipMemsetAsync(ws + (4u << 20) + 2 * 32768, 0, 2 * 32768, stream);

  prep_kernel<<<4096, 256, 0, stream>>>(fa, fb, abf, bbf, rna, rnb);
  gemm_kernel<<<dim3(64, 64), 256, 0, stream>>>(abf, bbf, rna, rnb, lab, out,
                                                lrow, srow);
  loss_kernel<<<1, 1024, 0, stream>>>(lab, lrow, srow, out);
}